// Round 11
// baseline (150.134 us; speedup 1.0000x reference)
//
#include <hip/hip_runtime.h>
#include <cstddef>

constexpr int Bn = 16, Dn = 512, Nn = 4096, Kn = 64;
constexpr int PN = 128;            // panel n-size
constexpr int Dp = 520;            // padded aggp pitch (non-pow2, 16B-aligned)
constexpr float FEPS = 1e-12f;

typedef __bf16 bf16x8 __attribute__((ext_vector_type(8)));
typedef float f32x4 __attribute__((ext_vector_type(4)));

__device__ __forceinline__ unsigned short bf_bits(__bf16 h) {
  union { __bf16 b; unsigned short u; } c;
  c.b = h;
  return c.u;
}

// ---------------------------------------------------------------------------
// kW: split conv_w[K][D] (row-major, d-contiguous) into bf16 hi/lo arrays.
// ---------------------------------------------------------------------------
__global__ __launch_bounds__(256) void kW(const float* __restrict__ w,
                                          unsigned short* __restrict__ w_hi,
                                          unsigned short* __restrict__ w_lo) {
  const int idx = blockIdx.x * 256 + threadIdx.x;  // 32768 total
  const float v = w[idx];
  const __bf16 h = (__bf16)v;          // RNE
  const float r = v - (float)h;
  const __bf16 l = (__bf16)r;
  w_hi[idx] = bf_bits(h);
  w_lo[idx] = bf_bits(l);
}

// ---------------------------------------------------------------------------
// kF v3: fused logits+softmax+agg. One block = one (b, 128-n panel),
// 512 threads = 8 waves, grid 512 = 2 blocks/CU.
// ROUND-11 CHANGE (sync structure only; math bit-identical to validated v2):
//   - phase-1 chunk loop uses RAW s_barrier + lgkmcnt(0) (no vmcnt drain!)
//     so global prefetch loads stay in flight across barriers (T4).
//   - 2-deep register prefetch (pfA/pfB), statically rotated (rule #20).
//   - 64-d chunks (8 iters): staging = full 64B/lane lines, half the barriers.
// Phase 2 unchanged (validated).
// ---------------------------------------------------------------------------
__global__ __launch_bounds__(512, 4) void kF(const float* __restrict__ x,
                                             const unsigned short* __restrict__ w_hi,
                                             const unsigned short* __restrict__ w_lo,
                                             const float* __restrict__ conv_b,
                                             float* __restrict__ aggp,
                                             float* __restrict__ massp) {
  __shared__ float smem[2 * PN * 66];  // 67.6 KB: xs dbuf; reused as assign
  __shared__ float msum[8][64];
  const int tid = threadIdx.x;
  const int l = tid & 63;
  const int wv = tid >> 6;   // 0..7
  const int ll = l & 15;
  const int lg = l >> 4;
  const int b = blockIdx.x >> 5;
  const int p = blockIdx.x & 31;
  const int n0 = p << 7;
  const float* xb = x + (size_t)b * Dn * Nn + n0;

  // ===================== Phase 1: logits =====================
  f32x4 acc[4];
#pragma unroll
  for (int kt = 0; kt < 4; ++kt) acc[kt] = (f32x4){0.f, 0.f, 0.f, 0.f};
  float ss = 0.f;

  // staging role: row srow (0..63) of each 64-d chunk, 64B span sc0..sc0+15
  const int srow = tid >> 3;
  const int sc0 = (tid & 7) << 4;
  const float* xsrc = xb + (size_t)srow * Nn + sc0;
  const int ncol = (wv << 4) + ll;

  float4 pfA[4], pfB[4];
#pragma unroll
  for (int q = 0; q < 4; ++q) pfA[q] = *(const float4*)(xsrc + 4 * q);
#pragma unroll
  for (int q = 0; q < 4; ++q)
    pfB[q] = *(const float4*)(xsrc + (size_t)64 * Nn + 4 * q);

#define KF_CONSUME(XS, DC)                                                    \
  {                                                                           \
    const float* xcol = (XS) + ncol * 66;                                     \
    _Pragma("unroll") for (int s = 0; s < 2; ++s) {                           \
      float xv[8];                                                            \
      _Pragma("unroll") for (int j = 0; j < 8; ++j)                           \
          xv[j] = xcol[s * 32 + lg * 8 + j];                                  \
      bf16x8 bh, bl;                                                          \
      _Pragma("unroll") for (int j = 0; j < 8; ++j) {                         \
        ss = fmaf(xv[j], xv[j], ss);                                          \
        const __bf16 h = (__bf16)xv[j];                                       \
        bh[j] = h;                                                            \
        bl[j] = (__bf16)(xv[j] - (float)h);                                   \
      }                                                                       \
      _Pragma("unroll") for (int kt = 0; kt < 4; ++kt) {                      \
        const size_t woff = (size_t)(kt * 16 + ll) * Dn + (DC) + s * 32 + lg * 8; \
        bf16x8 ah = *(const bf16x8*)(w_hi + woff);                            \
        bf16x8 al = *(const bf16x8*)(w_lo + woff);                            \
        acc[kt] = __builtin_amdgcn_mfma_f32_16x16x32_bf16(ah, bh, acc[kt], 0, 0, 0); \
        acc[kt] = __builtin_amdgcn_mfma_f32_16x16x32_bf16(ah, bl, acc[kt], 0, 0, 0); \
        acc[kt] = __builtin_amdgcn_mfma_f32_16x16x32_bf16(al, bh, acc[kt], 0, 0, 0); \
      }                                                                       \
    }                                                                         \
  }

#pragma unroll
  for (int it = 0; it < 4; ++it) {
    {  // even chunk 2*it -> buffer 0
      float* xs = smem;
#pragma unroll
      for (int q = 0; q < 4; ++q)
#pragma unroll
        for (int j = 0; j < 4; ++j)
          xs[(sc0 + 4 * q + j) * 66 + srow] = ((const float*)&pfA[q])[j];
      if (it < 3) {
#pragma unroll
        for (int q = 0; q < 4; ++q)
          pfA[q] = *(const float4*)(xsrc + (size_t)(it * 128 + 128) * Nn + 4 * q);
      }
      asm volatile("s_waitcnt lgkmcnt(0)" ::: "memory");
      __builtin_amdgcn_s_barrier();
      KF_CONSUME(xs, it * 128);
    }
    {  // odd chunk 2*it+1 -> buffer 1
      float* xs = smem + PN * 66;
#pragma unroll
      for (int q = 0; q < 4; ++q)
#pragma unroll
        for (int j = 0; j < 4; ++j)
          xs[(sc0 + 4 * q + j) * 66 + srow] = ((const float*)&pfB[q])[j];
      if (it < 3) {
#pragma unroll
        for (int q = 0; q < 4; ++q)
          pfB[q] = *(const float4*)(xsrc + (size_t)(it * 128 + 192) * Nn + 4 * q);
      }
      asm volatile("s_waitcnt lgkmcnt(0)" ::: "memory");
      __builtin_amdgcn_s_barrier();
      KF_CONSUME(xs, it * 128 + 64);
    }
  }
#undef KF_CONSUME

  // ---- softmax (in-register, per 16-n subtile) ----
  ss += __shfl_xor(ss, 16);
  ss += __shfl_xor(ss, 32);
  const float iv = 1.f / fmaxf(sqrtf(ss), FEPS);
  float lgt[16];
#pragma unroll
  for (int kt = 0; kt < 4; ++kt)
#pragma unroll
    for (int r = 0; r < 4; ++r)
      lgt[kt * 4 + r] = fmaf(acc[kt][r], iv, conv_b[kt * 16 + lg * 4 + r]);
  float pmax = lgt[0];
#pragma unroll
  for (int i = 1; i < 16; ++i) pmax = fmaxf(pmax, lgt[i]);
  pmax = fmaxf(pmax, __shfl_xor(pmax, 16));
  pmax = fmaxf(pmax, __shfl_xor(pmax, 32));
  float ex[16];
  float psum = 0.f;
#pragma unroll
  for (int i = 0; i < 16; ++i) {
    ex[i] = expf(lgt[i] - pmax);
    psum += ex[i];
  }
  psum += __shfl_xor(psum, 16);
  psum += __shfl_xor(psum, 32);
  const float isum = 1.f / psum;

  __syncthreads();  // all xs reads done before smem reused as assign

  // ---- assign hi/lo bf16 into LDS ([ng][k][8]) + mass partials ----
  unsigned short* as_hi = (unsigned short*)smem;          // 16 KB
  unsigned short* as_lo = as_hi + PN * Kn;                // 16 KB
  const int ngb = (wv << 1) + (ll >> 3);
  const int jj = ll & 7;
#pragma unroll
  for (int i = 0; i < 16; ++i) {
    const int k = (i >> 2) * 16 + lg * 4 + (i & 3);
    const float a = ex[i] * isum;
    const float v = a * iv;
    const __bf16 h = (__bf16)v;
    as_hi[(ngb * 64 + k) * 8 + jj] = bf_bits(h);
    as_lo[(ngb * 64 + k) * 8 + jj] = bf_bits((__bf16)(v - (float)h));
    float m = a;
    m += __shfl_xor(m, 1);
    m += __shfl_xor(m, 2);
    m += __shfl_xor(m, 4);
    m += __shfl_xor(m, 8);
    if (ll == 0) msum[wv][k] = m;
  }
  __syncthreads();  // assign + msum visible to all
  if (tid < 64) {
    float s = 0.f;
#pragma unroll
    for (int ww = 0; ww < 8; ++ww) s += msum[ww][tid];
    massp[((b << 5) + p) * Kn + tid] = s;
  }

  // ===================== Phase 2: agg partial =====================
  // wave wv -> d in [wv*64, wv*64+64); M=k, N=d, K=n(panel)
  f32x4 acc2[4][4];
#pragma unroll
  for (int kt = 0; kt < 4; ++kt)
#pragma unroll
    for (int dt = 0; dt < 4; ++dt) acc2[kt][dt] = (f32x4){0.f, 0.f, 0.f, 0.f};

  const float* xq = x + (size_t)b * Dn * Nn +
                    (size_t)(wv * 64 + ll) * Nn + n0 + lg * 8;

#pragma unroll
  for (int nc = 0; nc < PN; nc += 32) {
    const int ng = (nc >> 3) + lg;
    bf16x8 af_h[4], af_l[4];
#pragma unroll
    for (int kt = 0; kt < 4; ++kt) {
      const int idx = (ng * 64 + kt * 16 + ll) * 8;
      af_h[kt] = *(const bf16x8*)(as_hi + idx);
      af_l[kt] = *(const bf16x8*)(as_lo + idx);
    }
    bf16x8 bx[4];
#pragma unroll
    for (int dt = 0; dt < 4; ++dt) {
      const float* xr = xq + (size_t)(dt * 16) * Nn + nc;
      float4 x0 = *(const float4*)(xr);
      float4 x1 = *(const float4*)(xr + 4);
      bx[dt][0] = (__bf16)x0.x; bx[dt][1] = (__bf16)x0.y;
      bx[dt][2] = (__bf16)x0.z; bx[dt][3] = (__bf16)x0.w;
      bx[dt][4] = (__bf16)x1.x; bx[dt][5] = (__bf16)x1.y;
      bx[dt][6] = (__bf16)x1.z; bx[dt][7] = (__bf16)x1.w;
    }
#pragma unroll
    for (int kt = 0; kt < 4; ++kt)
#pragma unroll
      for (int dt = 0; dt < 4; ++dt) {
        acc2[kt][dt] = __builtin_amdgcn_mfma_f32_16x16x32_bf16(
            af_h[kt], bx[dt], acc2[kt][dt], 0, 0, 0);
        acc2[kt][dt] = __builtin_amdgcn_mfma_f32_16x16x32_bf16(
            af_l[kt], bx[dt], acc2[kt][dt], 0, 0, 0);
      }
  }

  // store partials: aggp[((b*32+p)*64 + k)*Dp + d]
  float* outb = aggp + (size_t)((b << 5) + p) * Kn * Dp;
#pragma unroll
  for (int kt = 0; kt < 4; ++kt)
#pragma unroll
    for (int dt = 0; dt < 4; ++dt) {
      const int krow = kt * 16 + (lg << 2);
      const int dcol = wv * 64 + dt * 16 + ll;
      float* op = outb + (size_t)krow * Dp + dcol;
#pragma unroll
      for (int r = 0; r < 4; ++r) op[(size_t)r * Dp] = acc2[kt][dt][r];
    }
}

// ---------------------------------------------------------------------------
// kC1: per (b,k): mass from massp (32 panels); vlad = sum(aggp over 32
// panels) - mass*c; intra-normalize over d.
// ---------------------------------------------------------------------------
__device__ __forceinline__ float blockReduceSum(float v, float* sb) {
#pragma unroll
  for (int off = 32; off > 0; off >>= 1) v += __shfl_down(v, off, 64);
  const int lane = threadIdx.x & 63, w = threadIdx.x >> 6;
  if (lane == 0) sb[w] = v;
  __syncthreads();
  if (threadIdx.x == 0) sb[4] = sb[0] + sb[1] + sb[2] + sb[3];
  __syncthreads();
  return sb[4];
}

__global__ __launch_bounds__(256) void kC1(const float* __restrict__ massp,
                                           const float* __restrict__ aggp,
                                           const float* __restrict__ centroids,
                                           float* __restrict__ out,
                                           float* __restrict__ rowsq) {
  __shared__ float sb[5];
  const int tid = threadIdx.x;
  const int b = blockIdx.x >> 6, k = blockIdx.x & 63;
  float s = 0.f;
  if (tid < 32) s = massp[((b << 5) + tid) * Kn + k];
  const float mass = blockReduceSum(s, sb);
  float v[2];
  float sq = 0.f;
#pragma unroll
  for (int u = 0; u < 2; ++u) {
    const int d = tid + (u << 8);
    float val = -mass * centroids[k * Dn + d];
#pragma unroll 8
    for (int pp = 0; pp < 32; ++pp)
      val += aggp[((size_t)((b << 5) + pp) * Kn + k) * Dp + d];
    v[u] = val;
    sq = fmaf(val, val, sq);
  }
  const float rsq = blockReduceSum(sq, sb);
  const float inv = 1.f / fmaxf(sqrtf(rsq), FEPS);
#pragma unroll
  for (int u = 0; u < 2; ++u)
    out[((size_t)b * Kn + k) * Dn + tid + (u << 8)] = v[u] * inv;
  if (tid == 0) rowsq[b * Kn + k] = rsq * inv * inv;
}

// ---------------------------------------------------------------------------
// kC2: final global L2 norm per batch.
// ---------------------------------------------------------------------------
__global__ __launch_bounds__(256) void kC2(float* __restrict__ out,
                                           const float* __restrict__ rowsq) {
  __shared__ float sg;
  const int b = blockIdx.x, tid = threadIdx.x;
  float v = (tid < 64) ? rowsq[b * Kn + tid] : 0.f;
  if (tid < 64) {
#pragma unroll
    for (int off = 32; off > 0; off >>= 1) v += __shfl_down(v, off, 64);
  }
  if (tid == 0) sg = 1.f / fmaxf(sqrtf(v), FEPS);
  __syncthreads();
  const float inv = sg;
  float* ob = out + (size_t)b * (Kn * Dn);
  for (int t = tid; t < Kn * Dn; t += 256) ob[t] *= inv;
}

// ---------------------------------------------------------------------------
extern "C" void kernel_launch(void* const* d_in, const int* in_sizes, int n_in,
                              void* d_out, int out_size, void* d_ws,
                              size_t ws_size, hipStream_t stream) {
  const float* x = (const float*)d_in[0];
  const float* centroids = (const float*)d_in[1];
  const float* conv_w = (const float*)d_in[2];
  const float* conv_b = (const float*)d_in[3];
  float* out = (float*)d_out;
  float* ws = (float*)d_ws;
  // ws layout (float units):
  //   aggp    [0,        17039360)  16 b x 32 p x 64 k x Dp(520) f32
  //   w_hi    [17039360, 17055744)  64x512 bf16 = 16384 floats
  //   w_lo    [17055744, 17072128)
  //   massp   [17072128, 17104896)  16 b x 32 p x 64 k
  //   rowsq   [17104896, 17105920)
  float* aggp = ws;
  unsigned short* w_hi = (unsigned short*)(ws + 17039360);
  unsigned short* w_lo = (unsigned short*)(ws + 17055744);
  float* massp = ws + 17072128;
  float* rowsq = ws + 17104896;

  kW<<<128, 256, 0, stream>>>(conv_w, w_hi, w_lo);
  kF<<<512, 512, 0, stream>>>(x, w_hi, w_lo, conv_b, aggp, massp);
  kC1<<<1024, 256, 0, stream>>>(massp, aggp, centroids, out, rowsq);
  kC2<<<16, 256, 0, stream>>>(out, rowsq);
}

// Round 12
// 123.212 us; speedup vs baseline: 1.2185x; 1.2185x over previous
//
#include <hip/hip_runtime.h>
#include <cstddef>

constexpr int Bn = 16, Dn = 512, Nn = 4096, Kn = 64;
constexpr int PN = 128;            // panel n-size
constexpr int Dp = 520;            // padded aggp pitch (non-pow2)
constexpr float FEPS = 1e-12f;

typedef __bf16 bf16x8 __attribute__((ext_vector_type(8)));
typedef float f32x4 __attribute__((ext_vector_type(4)));

__device__ __forceinline__ unsigned short bf_bits(__bf16 h) {
  union { __bf16 b; unsigned short u; } c;
  c.b = h;
  return c.u;
}

// ---------------------------------------------------------------------------
// kW: split conv_w[K][D] (row-major, d-contiguous) into bf16 hi/lo arrays.
// ---------------------------------------------------------------------------
__global__ __launch_bounds__(256) void kW(const float* __restrict__ w,
                                          unsigned short* __restrict__ w_hi,
                                          unsigned short* __restrict__ w_lo) {
  const int idx = blockIdx.x * 256 + threadIdx.x;  // 32768 total
  const float v = w[idx];
  const __bf16 h = (__bf16)v;          // RNE
  const float r = v - (float)h;
  const __bf16 l = (__bf16)r;
  w_hi[idx] = bf_bits(h);
  w_lo[idx] = bf_bits(l);
}

// ---------------------------------------------------------------------------
// kF v4: fused logits+softmax+agg with PERSISTENT LDS x-panel.
// Traffic cuts vs v3: phase 2 reads x from LDS (bf16-hi panel built for free
// during phase-1 staging), and each block accumulates agg over TWO panels in
// registers before writing (aggp partials 32 -> 16 per b).
// Block = (b, superpanel sp of 256 n), 512 thr = 8 waves, grid 256 = 1/CU.
// LDS: xhi[512][128] bf16 XOR-swizzled (128 KB, phase-2 B-frags),
//      xs[128][33] fp32 staging (16.9 KB, reused as as_hi in phase 2),
//      msum 2 KB.  Total ~147 KB.
// Phase-1 math bit-identical to validated v2/v3 (3-term bf16-split logits,
// in-register softmax). Phase-2 A = as_hi only (a*iv bf16-hi), B = bf16-hi x.
// ---------------------------------------------------------------------------
__global__ __launch_bounds__(512, 2) void kF(const float* __restrict__ x,
                                             const unsigned short* __restrict__ w_hi,
                                             const unsigned short* __restrict__ w_lo,
                                             const float* __restrict__ conv_b,
                                             float* __restrict__ aggp,
                                             float* __restrict__ massp) {
  __shared__ float xs[PN * 33];             // staging / as_hi reuse
  __shared__ unsigned short xhi[Dn * PN];   // persistent bf16-hi panel
  __shared__ float msum[8][64];
  const int tid = threadIdx.x;
  const int l = tid & 63;
  const int wv = tid >> 6;   // 0..7
  const int ll = l & 15;
  const int lg = l >> 4;
  const int b = blockIdx.x >> 4;
  const int sp = blockIdx.x & 15;
  const int srow = tid >> 4;        // 0..31 (staging row within 32-d chunk)
  const int sc0 = (tid & 15) << 3;  // staging col (8 n per thread)
  const int ncol = (wv << 4) + ll;  // phase-1 n within panel

  f32x4 acc2[4][4];
#pragma unroll
  for (int kt = 0; kt < 4; ++kt)
#pragma unroll
    for (int dt = 0; dt < 4; ++dt) acc2[kt][dt] = (f32x4){0.f, 0.f, 0.f, 0.f};

  for (int rep = 0; rep < 2; ++rep) {
    const int p = (sp << 1) + rep;
    const int n0 = p << 7;
    const float* xbp = x + (size_t)b * Dn * Nn + n0;

    // =================== Phase 1: logits (validated math) ===================
    f32x4 acc[4];
#pragma unroll
    for (int kt = 0; kt < 4; ++kt) acc[kt] = (f32x4){0.f, 0.f, 0.f, 0.f};
    float ss = 0.f;

    float4 pf0 = *(const float4*)(xbp + (size_t)srow * Nn + sc0);
    float4 pf1 = *(const float4*)(xbp + (size_t)srow * Nn + sc0 + 4);

    for (int dc = 0; dc < Dn; dc += 32) {
      // stage fp32 transposed [n][33] + bf16-hi into persistent panel
      const float pv[8] = {pf0.x, pf0.y, pf0.z, pf0.w, pf1.x, pf1.y, pf1.z, pf1.w};
#pragma unroll
      for (int j = 0; j < 8; ++j) xs[(sc0 + j) * 33 + srow] = pv[j];
      {
        unsigned short hb[8];
#pragma unroll
        for (int j = 0; j < 8; ++j) hb[j] = bf_bits((__bf16)pv[j]);
        const unsigned byteoff =
            (unsigned)(((dc + srow) * PN + sc0) * 2) ^ ((unsigned)(srow & 7) << 4);
        uint4 hv;
        hv.x = (unsigned)hb[0] | ((unsigned)hb[1] << 16);
        hv.y = (unsigned)hb[2] | ((unsigned)hb[3] << 16);
        hv.z = (unsigned)hb[4] | ((unsigned)hb[5] << 16);
        hv.w = (unsigned)hb[6] | ((unsigned)hb[7] << 16);
        *(uint4*)((char*)xhi + byteoff) = hv;
      }
      if (dc + 32 < Dn) {
        pf0 = *(const float4*)(xbp + (size_t)(dc + 32 + srow) * Nn + sc0);
        pf1 = *(const float4*)(xbp + (size_t)(dc + 32 + srow) * Nn + sc0 + 4);
      }
      asm volatile("s_waitcnt lgkmcnt(0)\ns_barrier" ::: "memory");

      // consume chunk
      float xv[8];
#pragma unroll
      for (int j = 0; j < 8; ++j) xv[j] = xs[ncol * 33 + lg * 8 + j];
      bf16x8 bh, bl;
#pragma unroll
      for (int j = 0; j < 8; ++j) {
        ss = fmaf(xv[j], xv[j], ss);
        const __bf16 h = (__bf16)xv[j];
        bh[j] = h;
        bl[j] = (__bf16)(xv[j] - (float)h);
      }
#pragma unroll
      for (int kt = 0; kt < 4; ++kt) {
        const size_t woff = (size_t)(kt * 16 + ll) * Dn + dc + lg * 8;
        bf16x8 ah = *(const bf16x8*)(w_hi + woff);
        bf16x8 al = *(const bf16x8*)(w_lo + woff);
        acc[kt] = __builtin_amdgcn_mfma_f32_16x16x32_bf16(ah, bh, acc[kt], 0, 0, 0);
        acc[kt] = __builtin_amdgcn_mfma_f32_16x16x32_bf16(ah, bl, acc[kt], 0, 0, 0);
        acc[kt] = __builtin_amdgcn_mfma_f32_16x16x32_bf16(al, bh, acc[kt], 0, 0, 0);
      }
      asm volatile("s_waitcnt lgkmcnt(0)\ns_barrier" ::: "memory");
    }

    // ---- softmax (in-register, validated) ----
    ss += __shfl_xor(ss, 16);
    ss += __shfl_xor(ss, 32);
    const float iv = 1.f / fmaxf(sqrtf(ss), FEPS);
    float lgt[16];
#pragma unroll
    for (int kt = 0; kt < 4; ++kt)
#pragma unroll
      for (int r = 0; r < 4; ++r)
        lgt[kt * 4 + r] = fmaf(acc[kt][r], iv, conv_b[kt * 16 + lg * 4 + r]);
    float pmax = lgt[0];
#pragma unroll
    for (int i = 1; i < 16; ++i) pmax = fmaxf(pmax, lgt[i]);
    pmax = fmaxf(pmax, __shfl_xor(pmax, 16));
    pmax = fmaxf(pmax, __shfl_xor(pmax, 32));
    float ex[16];
    float psum = 0.f;
#pragma unroll
    for (int i = 0; i < 16; ++i) {
      ex[i] = expf(lgt[i] - pmax);
      psum += ex[i];
    }
    psum += __shfl_xor(psum, 16);
    psum += __shfl_xor(psum, 32);
    const float isum = 1.f / psum;

    __syncthreads();  // xs reads done; reuse as as_hi

    unsigned short* as_hi = (unsigned short*)xs;  // [ng16][k64][8] bf16
    const int ngb = (wv << 1) + (ll >> 3);
    const int jj = ll & 7;
#pragma unroll
    for (int i = 0; i < 16; ++i) {
      const int k = (i >> 2) * 16 + lg * 4 + (i & 3);
      const float a = ex[i] * isum;
      as_hi[(ngb * 64 + k) * 8 + jj] = bf_bits((__bf16)(a * iv));
      float m = a;
      m += __shfl_xor(m, 1);
      m += __shfl_xor(m, 2);
      m += __shfl_xor(m, 4);
      m += __shfl_xor(m, 8);
      if (ll == 0) msum[wv][k] = m;
    }
    __syncthreads();
    if (tid < 64) {
      float s = 0.f;
#pragma unroll
      for (int ww = 0; ww < 8; ++ww) s += msum[ww][tid];
      massp[((b << 5) + p) * Kn + tid] = s;
    }

    // =================== Phase 2: agg from LDS ===================
    // wave wv -> d in [wv*64, wv*64+64); A = as_hi (LDS), B = xhi (LDS)
#pragma unroll
    for (int nc = 0; nc < PN; nc += 32) {
      const int ng = (nc >> 3) + lg;
      bf16x8 af[4];
#pragma unroll
      for (int kt = 0; kt < 4; ++kt)
        af[kt] = *(const bf16x8*)(as_hi + (ng * 64 + kt * 16 + ll) * 8);
#pragma unroll
      for (int dt = 0; dt < 4; ++dt) {
        const int d = wv * 64 + dt * 16 + ll;
        const unsigned byteoff =
            (unsigned)((d * PN + nc + lg * 8) * 2) ^ ((unsigned)(d & 7) << 4);
        bf16x8 bx = *(const bf16x8*)((const char*)xhi + byteoff);
#pragma unroll
        for (int kt = 0; kt < 4; ++kt)
          acc2[kt][dt] = __builtin_amdgcn_mfma_f32_16x16x32_bf16(
              af[kt], bx, acc2[kt][dt], 0, 0, 0);
      }
    }
    __syncthreads();  // phase-2 LDS reads done before next rep overwrites
  }

  // store partials: aggp[((b*16+sp)*64 + k)*Dp + d]
  float* outb = aggp + (size_t)((b << 4) + sp) * Kn * Dp;
#pragma unroll
  for (int kt = 0; kt < 4; ++kt)
#pragma unroll
    for (int dt = 0; dt < 4; ++dt) {
      const int krow = kt * 16 + (lg << 2);
      const int dcol = wv * 64 + dt * 16 + ll;
      float* op = outb + (size_t)krow * Dp + dcol;
#pragma unroll
      for (int r = 0; r < 4; ++r) op[(size_t)r * Dp] = acc2[kt][dt][r];
    }
}

// ---------------------------------------------------------------------------
// kC1: per (b,k): mass from massp (32 panels); vlad = sum(aggp over 16
// superpanels) - mass*c; intra-normalize over d.
// ---------------------------------------------------------------------------
__device__ __forceinline__ float blockReduceSum(float v, float* sb) {
#pragma unroll
  for (int off = 32; off > 0; off >>= 1) v += __shfl_down(v, off, 64);
  const int lane = threadIdx.x & 63, w = threadIdx.x >> 6;
  if (lane == 0) sb[w] = v;
  __syncthreads();
  if (threadIdx.x == 0) sb[4] = sb[0] + sb[1] + sb[2] + sb[3];
  __syncthreads();
  return sb[4];
}

__global__ __launch_bounds__(256) void kC1(const float* __restrict__ massp,
                                           const float* __restrict__ aggp,
                                           const float* __restrict__ centroids,
                                           float* __restrict__ out,
                                           float* __restrict__ rowsq) {
  __shared__ float sb[5];
  const int tid = threadIdx.x;
  const int b = blockIdx.x >> 6, k = blockIdx.x & 63;
  float s = 0.f;
  if (tid < 32) s = massp[((b << 5) + tid) * Kn + k];
  const float mass = blockReduceSum(s, sb);
  float v[2];
  float sq = 0.f;
#pragma unroll
  for (int u = 0; u < 2; ++u) {
    const int d = tid + (u << 8);
    float val = -mass * centroids[k * Dn + d];
#pragma unroll
    for (int pp = 0; pp < 16; ++pp)
      val += aggp[((size_t)((b << 4) + pp) * Kn + k) * Dp + d];
    v[u] = val;
    sq = fmaf(val, val, sq);
  }
  const float rsq = blockReduceSum(sq, sb);
  const float inv = 1.f / fmaxf(sqrtf(rsq), FEPS);
#pragma unroll
  for (int u = 0; u < 2; ++u)
    out[((size_t)b * Kn + k) * Dn + tid + (u << 8)] = v[u] * inv;
  if (tid == 0) rowsq[b * Kn + k] = rsq * inv * inv;
}

// ---------------------------------------------------------------------------
// kC2: final global L2 norm per batch.
// ---------------------------------------------------------------------------
__global__ __launch_bounds__(256) void kC2(float* __restrict__ out,
                                           const float* __restrict__ rowsq) {
  __shared__ float sg;
  const int b = blockIdx.x, tid = threadIdx.x;
  float v = (tid < 64) ? rowsq[b * Kn + tid] : 0.f;
  if (tid < 64) {
#pragma unroll
    for (int off = 32; off > 0; off >>= 1) v += __shfl_down(v, off, 64);
  }
  if (tid == 0) sg = 1.f / fmaxf(sqrtf(v), FEPS);
  __syncthreads();
  const float inv = sg;
  float* ob = out + (size_t)b * (Kn * Dn);
  for (int t = tid; t < Kn * Dn; t += 256) ob[t] *= inv;
}

// ---------------------------------------------------------------------------
extern "C" void kernel_launch(void* const* d_in, const int* in_sizes, int n_in,
                              void* d_out, int out_size, void* d_ws,
                              size_t ws_size, hipStream_t stream) {
  const float* x = (const float*)d_in[0];
  const float* centroids = (const float*)d_in[1];
  const float* conv_w = (const float*)d_in[2];
  const float* conv_b = (const float*)d_in[3];
  float* out = (float*)d_out;
  float* ws = (float*)d_ws;
  // ws layout (float units):
  //   aggp    [0,        8519680)  16 b x 16 sp x 64 k x Dp(520) f32
  //   w_hi    [8519680,  8536064)  64x512 bf16 = 16384 floats
  //   w_lo    [8536064,  8552448)
  //   massp   [8552448,  8585216)  16 b x 32 p x 64 k
  //   rowsq   [8585216,  8586240)
  float* aggp = ws;
  unsigned short* w_hi = (unsigned short*)(ws + 8519680);
  unsigned short* w_lo = (unsigned short*)(ws + 8536064);
  float* massp = ws + 8552448;
  float* rowsq = ws + 8585216;

  kW<<<128, 256, 0, stream>>>(conv_w, w_hi, w_lo);
  kF<<<256, 512, 0, stream>>>(x, w_hi, w_lo, conv_b, aggp, massp);
  kC1<<<1024, 256, 0, stream>>>(massp, aggp, centroids, out, rowsq);
  kC2<<<16, 256, 0, stream>>>(out, rowsq);
}